// Round 4
// baseline (647.635 us; speedup 1.0000x reference)
//
#include <hip/hip_runtime.h>
#include <stdint.h>

typedef unsigned short u16;
typedef __attribute__((ext_vector_type(8))) short short8;
typedef __attribute__((ext_vector_type(8))) __bf16 bf16x8;
typedef __attribute__((ext_vector_type(4))) float floatx4;

#define AS1 __attribute__((address_space(1)))
#define AS3 __attribute__((address_space(3)))

// ---- constants for this problem ----
// B=2, S=2048, D=1024, H=16, DH=64, FF=4096, M = B*S = 4096
// QSCALE = (1/sqrt(DH)) * log2(e): attention computed in exp2 domain.
#define QSCALE 0.18033688f

// round-to-nearest (ties-away) f32->bf16: 2 ops instead of 4-op RNE.
__device__ __forceinline__ u16 f2bf(float f) {
    union { float f; unsigned u; } v; v.f = f;
    return (u16)((v.u + 0x8000u) >> 16);
}

// async global->LDS, 16B per lane, LDS dest = wave-uniform base + lane*16
__device__ __forceinline__ void gl_lds16(const void* g, void* lds) {
    __builtin_amdgcn_global_load_lds((const AS1 unsigned int*)(uintptr_t)g,
                                     (AS3 unsigned int*)(uintptr_t)lds, 16, 0, 0);
}

__device__ __forceinline__ floatx4 mfma16(short8 a, short8 b, floatx4 c) {
    return __builtin_amdgcn_mfma_f32_16x16x32_bf16((bf16x8)a, (bf16x8)b, c, 0, 0, 0);
}

// ---------------- batched transpose of four 1024x1024 fp32 -> bf16 ----------
__global__ void transpose4_1024(const float* __restrict__ s0, const float* __restrict__ s1,
                                const float* __restrict__ s2, const float* __restrict__ s3,
                                u16* __restrict__ d) {
    __shared__ float tile[32][33];
    const float* srcs[4] = {s0, s1, s2, s3};
    const float* src = srcs[blockIdx.z];
    u16* dst = d + (size_t)blockIdx.z * 1024 * 1024;
    int c0 = blockIdx.x * 32, r0 = blockIdx.y * 32;
    int tx = threadIdx.x, ty = threadIdx.y;  // (32,8)
#pragma unroll
    for (int i = 0; i < 4; i++)
        tile[ty + i * 8][tx] = src[(size_t)(r0 + ty + i * 8) * 1024 + c0 + tx];
    __syncthreads();
#pragma unroll
    for (int i = 0; i < 4; i++)
        dst[(size_t)(c0 + ty + i * 8) * 1024 + r0 + tx] = f2bf(tile[tx][ty + i * 8]);
}

// ---------------- transpose fp32 (R,C) -> bf16 (C,R) ----------------
__global__ void transpose_f32_to_bf16(const float* __restrict__ src, u16* __restrict__ dst,
                                      int R, int C) {
    __shared__ float tile[32][33];
    int c0 = blockIdx.x * 32, r0 = blockIdx.y * 32;
    int tx = threadIdx.x, ty = threadIdx.y;  // (32,8)
#pragma unroll
    for (int i = 0; i < 4; i++)
        tile[ty + i * 8][tx] = src[(size_t)(r0 + ty + i * 8) * C + c0 + tx];
    __syncthreads();
#pragma unroll
    for (int i = 0; i < 4; i++)
        dst[(size_t)(c0 + ty + i * 8) * R + r0 + tx] = f2bf(tile[tx][ty + i * 8]);
}

__global__ void convert_to_bf16(const float* __restrict__ s, u16* __restrict__ d, int n) {
    int i = blockIdx.x * 256 + threadIdx.x;
    if (i < n) d[i] = f2bf(s[i]);
}

// ---------------- layernorm over D=1024: writes fp32 + bf16 ----------------
__global__ __launch_bounds__(256) void ln_kernel(const float* __restrict__ x,
                                                 const float* __restrict__ g,
                                                 const float* __restrict__ bt,
                                                 float* __restrict__ yf,
                                                 u16* __restrict__ yb) {
    const int row = blockIdx.x, tid = threadIdx.x;
    const float4 xv = ((const float4*)(x + (size_t)row * 1024))[tid];
    float s = xv.x + xv.y + xv.z + xv.w;
    float sq = xv.x * xv.x + xv.y * xv.y + xv.z * xv.z + xv.w * xv.w;
#pragma unroll
    for (int m = 1; m < 64; m <<= 1) { s += __shfl_xor(s, m); sq += __shfl_xor(sq, m); }
    __shared__ float red[8];
    int w = tid >> 6;
    if ((tid & 63) == 0) { red[w] = s; red[4 + w] = sq; }
    __syncthreads();
    s = red[0] + red[1] + red[2] + red[3];
    sq = red[4] + red[5] + red[6] + red[7];
    float mean = s * (1.f / 1024.f);
    float var = sq * (1.f / 1024.f) - mean * mean;
    float rstd = rsqrtf(var + 1e-5f);
    float4 gv = ((const float4*)g)[tid];
    float4 bv = ((const float4*)bt)[tid];
    float4 y;
    y.x = (xv.x - mean) * rstd * gv.x + bv.x;
    y.y = (xv.y - mean) * rstd * gv.y + bv.y;
    y.z = (xv.z - mean) * rstd * gv.z + bv.z;
    y.w = (xv.w - mean) * rstd * gv.w + bv.w;
    ((float4*)(yf + (size_t)row * 1024))[tid] = y;
    ushort4 u;
    u.x = f2bf(y.x); u.y = f2bf(y.y); u.z = f2bf(y.z); u.w = f2bf(y.w);
    ((ushort4*)(yb + (size_t)row * 1024))[tid] = u;
}

// ---------------- GEMM 128x128, BK=64 swizzled: C = A(M,K) * Bt(N,K)^T ------
// outb = bf16(relu(acc+bias))   (used for FFN1)
__global__ __launch_bounds__(256) void gemm_bt(const u16* __restrict__ A,
                                               const u16* __restrict__ Bt,
                                               const float* __restrict__ bias,
                                               u16* __restrict__ outb,
                                               int M, int N, int K) {
    __shared__ __align__(16) u16 As[128 * 64];
    __shared__ __align__(16) u16 Bs[128 * 64];
    const int tid = threadIdx.x;
    const int w = tid >> 6, l = tid & 63, ln = l & 15, quad = l >> 4;
    const int m0 = blockIdx.y * 128, n0 = blockIdx.x * 128;
    const int wm = (w >> 1) * 64, wn = (w & 1) * 64;
    floatx4 acc[4][4] = {};

    for (int k0 = 0; k0 < K; k0 += 64) {
        __syncthreads();
#pragma unroll
        for (int r = 0; r < 4; r++) {
            int o = tid + r * 256;          // chunk id, 8 chunks/row (64 bf16)
            int row = o >> 3, c = (o & 7) ^ (row & 7);
            gl_lds16(&A[(size_t)(m0 + row) * K + k0 + c * 8], &As[(w * 64 + r * 256) * 8]);
            gl_lds16(&Bt[(size_t)(n0 + row) * K + k0 + c * 8], &Bs[(w * 64 + r * 256) * 8]);
        }
        __syncthreads();
#pragma unroll
        for (int kk = 0; kk < 2; kk++) {
            short8 av[4], bv[4];
#pragma unroll
            for (int mt = 0; mt < 4; mt++) {
                int rr = wm + mt * 16 + ln;
                av[mt] = *(const short8*)&As[rr * 64 + (((kk * 4 + quad) ^ (rr & 7)) * 8)];
            }
#pragma unroll
            for (int nt = 0; nt < 4; nt++) {
                int rr = wn + nt * 16 + ln;
                bv[nt] = *(const short8*)&Bs[rr * 64 + (((kk * 4 + quad) ^ (rr & 7)) * 8)];
            }
#pragma unroll
            for (int mt = 0; mt < 4; mt++)
#pragma unroll
                for (int nt = 0; nt < 4; nt++)
                    acc[mt][nt] = mfma16(av[mt], bv[nt], acc[mt][nt]);
        }
    }

#pragma unroll
    for (int nt = 0; nt < 4; nt++) {
        int n = n0 + wn + nt * 16 + ln;
        float bval = bias[n];
#pragma unroll
        for (int mt = 0; mt < 4; mt++) {
#pragma unroll
            for (int r = 0; r < 4; r++) {
                int m = m0 + wm + mt * 16 + quad * 4 + r;
                float v = acc[mt][nt][r] + bval;
                outb[(size_t)m * N + n] = f2bf(fmaxf(v, 0.f));
            }
        }
    }
}

// ---------------- fused QKV GEMM: N=3072 segmented epilogue, BK=64 ----------
__global__ __launch_bounds__(256) void gemm_qkv(const u16* __restrict__ A,
                                                const u16* __restrict__ Bt,
                                                const float* __restrict__ bq,
                                                const float* __restrict__ bk,
                                                const float* __restrict__ bv,
                                                u16* __restrict__ qb,
                                                u16* __restrict__ kb,
                                                u16* __restrict__ vtb) {
    constexpr int K = 1024;
    __shared__ __align__(16) u16 As[128 * 64];
    __shared__ __align__(16) u16 Bs[128 * 64];
    const int tid = threadIdx.x;
    const int w = tid >> 6, l = tid & 63, ln = l & 15, quad = l >> 4;
    const int m0 = blockIdx.y * 128, n0 = blockIdx.x * 128;
    const int wm = (w >> 1) * 64, wn = (w & 1) * 64;
    floatx4 acc[4][4] = {};

    for (int k0 = 0; k0 < K; k0 += 64) {
        __syncthreads();
#pragma unroll
        for (int r = 0; r < 4; r++) {
            int o = tid + r * 256;
            int row = o >> 3, c = (o & 7) ^ (row & 7);
            gl_lds16(&A[(size_t)(m0 + row) * K + k0 + c * 8], &As[(w * 64 + r * 256) * 8]);
            gl_lds16(&Bt[(size_t)(n0 + row) * K + k0 + c * 8], &Bs[(w * 64 + r * 256) * 8]);
        }
        __syncthreads();
#pragma unroll
        for (int kk = 0; kk < 2; kk++) {
            short8 av[4], bv4[4];
#pragma unroll
            for (int mt = 0; mt < 4; mt++) {
                int rr = wm + mt * 16 + ln;
                av[mt] = *(const short8*)&As[rr * 64 + (((kk * 4 + quad) ^ (rr & 7)) * 8)];
            }
#pragma unroll
            for (int nt = 0; nt < 4; nt++) {
                int rr = wn + nt * 16 + ln;
                bv4[nt] = *(const short8*)&Bs[rr * 64 + (((kk * 4 + quad) ^ (rr & 7)) * 8)];
            }
#pragma unroll
            for (int mt = 0; mt < 4; mt++)
#pragma unroll
                for (int nt = 0; nt < 4; nt++)
                    acc[mt][nt] = mfma16(av[mt], bv4[nt], acc[mt][nt]);
        }
    }

    const int seg = (n0 + wn) >> 10;  // wave-uniform: 0=q, 1=k, 2=v
#pragma unroll
    for (int nt = 0; nt < 4; nt++) {
        int nl = (n0 + wn + nt * 16 + ln) & 1023;
        float bval = seg == 0 ? bq[nl] : (seg == 1 ? bk[nl] : bv[nl]);
#pragma unroll
        for (int mt = 0; mt < 4; mt++) {
#pragma unroll
            for (int r = 0; r < 4; r++) {
                int m = m0 + wm + mt * 16 + quad * 4 + r;
                float v = acc[mt][nt][r] + bval;
                if (seg == 0) {
                    qb[(size_t)m * 1024 + nl] = f2bf(v * QSCALE);
                } else if (seg == 1) {
                    kb[(size_t)m * 1024 + nl] = f2bf(v);
                } else {
                    int b_ = m >> 11, s = m & 2047, hh = nl >> 6, d = nl & 63;
                    vtb[(((size_t)(b_ * 16 + hh)) * 64 + d) * 2048 + s] = f2bf(v);
                }
            }
        }
    }
}

// ---------------- GEMM 128x64 tile, BK=64 (N=1024 shapes, 512 blocks) -------
// out = acc + bias + resid (fp32)
__global__ __launch_bounds__(256) void gemm_bt64(const u16* __restrict__ A,
                                                 const u16* __restrict__ Bt,
                                                 const float* __restrict__ bias,
                                                 const float* __restrict__ resid,
                                                 float* __restrict__ outf,
                                                 int N, int K) {
    __shared__ __align__(16) u16 As[128 * 64];
    __shared__ __align__(16) u16 Bs[64 * 64];
    const int tid = threadIdx.x;
    const int w = tid >> 6, l = tid & 63, ln = l & 15, quad = l >> 4;
    const int m0 = blockIdx.y * 128, n0 = blockIdx.x * 64;
    const int wm = (w >> 1) * 64, wn = (w & 1) * 32;
    floatx4 acc[4][2] = {};

    for (int k0 = 0; k0 < K; k0 += 64) {
        __syncthreads();
#pragma unroll
        for (int r = 0; r < 4; r++) {
            int o = tid + r * 256;
            int row = o >> 3, c = (o & 7) ^ (row & 7);
            gl_lds16(&A[(size_t)(m0 + row) * K + k0 + c * 8], &As[(w * 64 + r * 256) * 8]);
        }
#pragma unroll
        for (int r = 0; r < 2; r++) {
            int o = tid + r * 256;
            int row = o >> 3, c = (o & 7) ^ (row & 7);
            gl_lds16(&Bt[(size_t)(n0 + row) * K + k0 + c * 8], &Bs[(w * 64 + r * 256) * 8]);
        }
        __syncthreads();
#pragma unroll
        for (int kk = 0; kk < 2; kk++) {
            short8 av[4], bv2[2];
#pragma unroll
            for (int mt = 0; mt < 4; mt++) {
                int rr = wm + mt * 16 + ln;
                av[mt] = *(const short8*)&As[rr * 64 + (((kk * 4 + quad) ^ (rr & 7)) * 8)];
            }
#pragma unroll
            for (int nt = 0; nt < 2; nt++) {
                int rr = wn + nt * 16 + ln;
                bv2[nt] = *(const short8*)&Bs[rr * 64 + (((kk * 4 + quad) ^ (rr & 7)) * 8)];
            }
#pragma unroll
            for (int mt = 0; mt < 4; mt++)
#pragma unroll
                for (int nt = 0; nt < 2; nt++)
                    acc[mt][nt] = mfma16(av[mt], bv2[nt], acc[mt][nt]);
        }
    }

#pragma unroll
    for (int nt = 0; nt < 2; nt++) {
        int n = n0 + wn + nt * 16 + ln;
        float bval = bias[n];
#pragma unroll
        for (int mt = 0; mt < 4; mt++) {
#pragma unroll
            for (int r = 0; r < 4; r++) {
                int m = m0 + wm + mt * 16 + quad * 4 + r;
                outf[(size_t)m * N + n] = acc[mt][nt][r] + bval + resid[(size_t)m * N + n];
            }
        }
    }
}

// ---------------- fused attention with relative-position skew ----------------
// exp2-domain, no online max. Q-tile 64 rows; 8 waves: qw=w&3 owns 16 Q rows,
// tw=w>>2 picks one of TWO t-tiles per iteration (t-split); partial O/l merge
// by addition at the end. Er A-fragments read straight from global (L1/L2-hot).
__global__ __launch_bounds__(512, 6) void attn_kernel(const u16* __restrict__ qb,
                                                      const u16* __restrict__ kb,
                                                      const u16* __restrict__ vtb,
                                                      const u16* __restrict__ erb,
                                                      u16* __restrict__ ob) {
    constexpr int S = 2048, D = 1024;
    const int s0 = blockIdx.x * 64, h = blockIdx.y, b = blockIdx.z;
    const int tid = threadIdx.x, w = tid >> 6, l = tid & 63, ln = l & 15, quad = l >> 4;
    const int qw = w & 3, tw = w >> 2;

    __shared__ __align__(16) u16 Ks[2][64 * 64];    // K tiles  [t][d swz]  16KB
    __shared__ __align__(16) u16 Vts[2][64 * 64];   // V^T tiles [d][t swz] 16KB
    __shared__ __align__(16) u16 Ps[8][16 * 72];    // per-wave P, stride72 18KB

    const u16* kbase = kb + ((size_t)b * S) * D + h * 64;
    const u16* vtbase = vtb + ((size_t)(b * 16 + h)) * 64 * S;

    const u16* qrow = qb + ((size_t)b * S + s0 + qw * 16 + ln) * D + h * 64;
    short8 aq[2];
    aq[0] = *(const short8*)&qrow[quad * 8];
    aq[1] = *(const short8*)&qrow[32 + quad * 8];

    const short8 ones8 = {16256, 16256, 16256, 16256, 16256, 16256, 16256, 16256};  // bf16 1.0

    // per-r gather constants: jcol = nt*16 + ln + 15 - quad*4 - r
    int srcl[4], carry[4];
#pragma unroll
    for (int r = 0; r < 4; r++) {
        srcl[r] = (l & 48) | ((ln + 15 - quad * 4 - r) & 15);
        carry[r] = (ln - quad * 4 - r) > 0 ? 1 : 0;
    }

    floatx4 accO[4] = {};
    floatx4 accL = {};
    const int srow_base = s0 + qw * 16 + quad * 4;

    for (int it = 0; it < S / 128; it++) {
        const int t0 = it * 128 + tw * 64;
        const bool bias_tile = (t0 <= s0);
        __syncthreads();
        {   // stage both K tiles and both V^T tiles (each thread: 2+2 chunks)
            int row = tid >> 3, sc = (tid & 7) ^ (row & 7);
#pragma unroll
            for (int tt = 0; tt < 2; tt++) {
                int tg = it * 128 + tt * 64;
                gl_lds16(&kbase[(size_t)(tg + row) * D + sc * 8], &Ks[tt][w * 512]);
                gl_lds16(&vtbase[(size_t)row * S + tg + sc * 8], &Vts[tt][w * 512]);
            }
        }
        __syncthreads();

        // S = Q K^T  (per wave: 16 rows x 64 cols of its t-tile)
        floatx4 sacc[4] = {};
#pragma unroll
        for (int kk = 0; kk < 2; kk++)
#pragma unroll
            for (int nt = 0; nt < 4; nt++) {
                int tr = nt * 16 + ln;
                short8 bk = *(const short8*)&Ks[tw][tr * 64 + (((kk * 4 + quad) ^ (tr & 7)) * 8)];
                sacc[nt] = mfma16(aq[kk], bk, sacc[nt]);
            }
        // G = Q ErBand^T, 80-col window; Er frags direct from global (L2-hot)
        floatx4 gacc[5] = {};
        if (bias_tile) {
            int jw0 = t0 - s0 - qw * 16 + 2032;  // >= 0 for all bias tiles
#pragma unroll
            for (int i = 0; i < 5; i++) {
                int j = jw0 + i * 16 + ln;
                j = j > S - 1 ? S - 1 : j;       // clamped rows are masked out
                const u16* ep = erb + (size_t)j * 64;
                short8 e0 = *(const short8*)&ep[quad * 8];
                short8 e1 = *(const short8*)&ep[32 + quad * 8];
                gacc[i] = mfma16(aq[0], e0, gacc[i]);
                gacc[i] = mfma16(aq[1], e1, gacc[i]);
            }
        }

        // p = exp2(score + bias); store P tile (bf16) for the PV MFMA
#pragma unroll
        for (int r = 0; r < 4; r++) {
            const int rloc = quad * 4 + r;
            const int srow = srow_base + r;
            float sh[5];
            if (bias_tile) {
#pragma unroll
                for (int i = 0; i < 5; i++) sh[i] = __shfl(gacc[i][r], srcl[r]);
            }
#pragma unroll
            for (int nt = 0; nt < 4; nt++) {
                float xv = sacc[nt][r];
                if (bias_tile) {
                    float g = carry[r] ? sh[nt + 1] : sh[nt];
                    bool mk = (t0 + nt * 16 + ln) <= srow;
                    xv += mk ? g : 0.f;
                }
                float p = __builtin_amdgcn_exp2f(xv);
                Ps[w][rloc * 72 + nt * 16 + ln] = f2bf(p);
            }
        }

        // O += P V ; l += P . ones   (all MFMA)
#pragma unroll
        for (int kk = 0; kk < 2; kk++) {
            short8 pf = *(const short8*)&Ps[w][ln * 72 + kk * 32 + quad * 8];
#pragma unroll
            for (int nt = 0; nt < 4; nt++) {
                int dr = nt * 16 + ln;
                short8 bv = *(const short8*)&Vts[tw][dr * 64 + (((kk * 4 + quad) ^ (dr & 7)) * 8)];
                accO[nt] = mfma16(pf, bv, accO[nt]);
            }
            accL = mfma16(pf, ones8, accL);
        }
    }

    // merge tw=1 partials into tw=0 (plain addition: exp2 domain, no max)
    __syncthreads();
    float* Om = (float*)&Ks[0][0];   // [4][16][64] f32 = 16KB (overlays Ks)
    float* Lm = (float*)&Vts[0][0];  // [4][16] f32
    if (tw == 1) {
#pragma unroll
        for (int nt = 0; nt < 4; nt++)
#pragma unroll
            for (int r = 0; r < 4; r++)
                Om[(qw * 16 + quad * 4 + r) * 64 + nt * 16 + ln] = accO[nt][r];
        if (ln == 0) {
#pragma unroll
            for (int r = 0; r < 4; r++) Lm[qw * 16 + quad * 4 + r] = accL[r];
        }
    }
    __syncthreads();
    if (tw == 0) {
#pragma unroll
        for (int r = 0; r < 4; r++) {
            float lsum = accL[r] + Lm[qw * 16 + quad * 4 + r];
            float inv = 1.f / lsum;
            int srow = srow_base + r;
#pragma unroll
            for (int nt = 0; nt < 4; nt++) {
                float val = (accO[nt][r] + Om[(qw * 16 + quad * 4 + r) * 64 + nt * 16 + ln]) * inv;
                ob[((size_t)b * S + srow) * D + h * 64 + nt * 16 + ln] = f2bf(val);
            }
        }
    }
}

// ---------------- launch ----------------
extern "C" void kernel_launch(void* const* d_in, const int* in_sizes, int n_in,
                              void* d_out, int out_size, void* d_ws, size_t ws_size,
                              hipStream_t stream) {
    const float* x   = (const float*)d_in[0];
    const float* Wq  = (const float*)d_in[1];
    const float* bq  = (const float*)d_in[2];
    const float* Wk  = (const float*)d_in[3];
    const float* bk  = (const float*)d_in[4];
    const float* Wv  = (const float*)d_in[5];
    const float* bv  = (const float*)d_in[6];
    const float* Wo  = (const float*)d_in[7];
    const float* bo  = (const float*)d_in[8];
    const float* Er  = (const float*)d_in[9];
    const float* W1  = (const float*)d_in[10];
    const float* b1  = (const float*)d_in[11];
    const float* W2  = (const float*)d_in[12];
    const float* b2  = (const float*)d_in[13];
    const float* g1  = (const float*)d_in[14];
    const float* be1 = (const float*)d_in[15];
    const float* g2  = (const float*)d_in[16];
    const float* be2 = (const float*)d_in[17];
    float* out = (float*)d_out;

    char* ws = (char*)d_ws;
    size_t off = 0;
    auto alloc_f = [&](size_t n) { float* p = (float*)(ws + off); off += n * 4; return p; };
    auto alloc_h = [&](size_t n) { u16* p = (u16*)(ws + off); off += n * 2; return p; };

    float* x1f = alloc_f((size_t)4096 * 1024);
    float* x2f = alloc_f((size_t)4096 * 1024);
    float* x3f = alloc_f((size_t)4096 * 1024);
    u16* x1b = alloc_h((size_t)4096 * 1024);
    u16* x3b = alloc_h((size_t)4096 * 1024);
    u16* qbf = alloc_h((size_t)4096 * 1024);   // } these four are contiguous:
    u16* kbf = alloc_h((size_t)4096 * 1024);   // } 32MB, reused as hbf for FFN
    u16* vtb = alloc_h((size_t)4096 * 1024);   // }
    u16* aob = alloc_h((size_t)4096 * 1024);   // }
    u16* WqT = alloc_h((size_t)1024 * 1024);   // } WqT/WkT/WvT contiguous = fused
    u16* WkT = alloc_h((size_t)1024 * 1024);   // } QKV weight (N=3072, K=1024)
    u16* WvT = alloc_h((size_t)1024 * 1024);   // }
    u16* WoT = alloc_h((size_t)1024 * 1024);
    u16* W1T = alloc_h((size_t)1024 * 4096);
    u16* W2T = alloc_h((size_t)1024 * 4096);
    u16* Erb = alloc_h((size_t)2048 * 64);
    u16* hbf = qbf;  // FFN hidden (4096x4096 bf16 = 32MB) aliases q/k/vT/attout
    (void)WkT; (void)WvT;

    dim3 tb(32, 8);
    transpose4_1024<<<dim3(32, 32, 4), tb, 0, stream>>>(Wq, Wk, Wv, Wo, WqT);
    transpose_f32_to_bf16<<<dim3(128, 32), tb, 0, stream>>>(W1, W1T, 1024, 4096);
    transpose_f32_to_bf16<<<dim3(32, 128), tb, 0, stream>>>(W2, W2T, 4096, 1024);
    convert_to_bf16<<<512, 256, 0, stream>>>(Er, Erb, 2048 * 64);

    ln_kernel<<<4096, 256, 0, stream>>>(x, g1, be1, x1f, x1b);

    // fused QKV: q=(x1 Wq+bq)*QSCALE (exp2 domain), k=x1 Wk+bk, v->(b,h,d,s)
    gemm_qkv<<<dim3(24, 32), 256, 0, stream>>>(x1b, WqT, bq, bk, bv, qbf, kbf, vtb);

    attn_kernel<<<dim3(32, 16, 2), 512, 0, stream>>>(qbf, kbf, vtb, Erb, aob);

    // x2 = x1 + attout Wo + bo
    gemm_bt64<<<dim3(16, 32), 256, 0, stream>>>(aob, WoT, bo, x1f, x2f, 1024, 1024);

    ln_kernel<<<4096, 256, 0, stream>>>(x2f, g2, be2, x3f, x3b);

    // h = relu(x3 W1 + b1) ; y = x3 + h W2 + b2
    gemm_bt<<<dim3(32, 32), 256, 0, stream>>>(x3b, W1T, b1, hbf, 4096, 4096, 1024);
    gemm_bt64<<<dim3(16, 32), 256, 0, stream>>>(hbf, W2T, b2, x3f, out, 1024, 4096);
}

// Round 5
// 490.439 us; speedup vs baseline: 1.3205x; 1.3205x over previous
//
#include <hip/hip_runtime.h>
#include <stdint.h>

typedef unsigned short u16;
typedef __attribute__((ext_vector_type(8))) short short8;
typedef __attribute__((ext_vector_type(8))) __bf16 bf16x8;
typedef __attribute__((ext_vector_type(4))) float floatx4;

#define AS1 __attribute__((address_space(1)))
#define AS3 __attribute__((address_space(3)))

// ---- constants for this problem ----
// B=2, S=2048, D=1024, H=16, DH=64, FF=4096, M = B*S = 4096
// QSCALE = (1/sqrt(DH)) * log2(e): attention computed in exp2 domain.
#define QSCALE 0.18033688f

// round-to-nearest (ties-away) f32->bf16: 2 ops instead of 4-op RNE.
__device__ __forceinline__ u16 f2bf(float f) {
    union { float f; unsigned u; } v; v.f = f;
    return (u16)((v.u + 0x8000u) >> 16);
}

// async global->LDS, 16B per lane, LDS dest = wave-uniform base + lane*16
__device__ __forceinline__ void gl_lds16(const void* g, void* lds) {
    __builtin_amdgcn_global_load_lds((const AS1 unsigned int*)(uintptr_t)g,
                                     (AS3 unsigned int*)(uintptr_t)lds, 16, 0, 0);
}

__device__ __forceinline__ floatx4 mfma16(short8 a, short8 b, floatx4 c) {
    return __builtin_amdgcn_mfma_f32_16x16x32_bf16((bf16x8)a, (bf16x8)b, c, 0, 0, 0);
}

// ---------------- batched transpose of four 1024x1024 fp32 -> bf16 ----------
__global__ void transpose4_1024(const float* __restrict__ s0, const float* __restrict__ s1,
                                const float* __restrict__ s2, const float* __restrict__ s3,
                                u16* __restrict__ d) {
    __shared__ float tile[32][33];
    const float* srcs[4] = {s0, s1, s2, s3};
    const float* src = srcs[blockIdx.z];
    u16* dst = d + (size_t)blockIdx.z * 1024 * 1024;
    int c0 = blockIdx.x * 32, r0 = blockIdx.y * 32;
    int tx = threadIdx.x, ty = threadIdx.y;  // (32,8)
#pragma unroll
    for (int i = 0; i < 4; i++)
        tile[ty + i * 8][tx] = src[(size_t)(r0 + ty + i * 8) * 1024 + c0 + tx];
    __syncthreads();
#pragma unroll
    for (int i = 0; i < 4; i++)
        dst[(size_t)(c0 + ty + i * 8) * 1024 + r0 + tx] = f2bf(tile[tx][ty + i * 8]);
}

// ---------------- transpose fp32 (R,C) -> bf16 (C,R) ----------------
__global__ void transpose_f32_to_bf16(const float* __restrict__ src, u16* __restrict__ dst,
                                      int R, int C) {
    __shared__ float tile[32][33];
    int c0 = blockIdx.x * 32, r0 = blockIdx.y * 32;
    int tx = threadIdx.x, ty = threadIdx.y;  // (32,8)
#pragma unroll
    for (int i = 0; i < 4; i++)
        tile[ty + i * 8][tx] = src[(size_t)(r0 + ty + i * 8) * C + c0 + tx];
    __syncthreads();
#pragma unroll
    for (int i = 0; i < 4; i++)
        dst[(size_t)(c0 + ty + i * 8) * R + r0 + tx] = f2bf(tile[tx][ty + i * 8]);
}

__global__ void convert_to_bf16(const float* __restrict__ s, u16* __restrict__ d, int n) {
    int i = blockIdx.x * 256 + threadIdx.x;
    if (i < n) d[i] = f2bf(s[i]);
}

// ---------------- layernorm over D=1024: writes fp32 + bf16 ----------------
__global__ __launch_bounds__(256) void ln_kernel(const float* __restrict__ x,
                                                 const float* __restrict__ g,
                                                 const float* __restrict__ bt,
                                                 float* __restrict__ yf,
                                                 u16* __restrict__ yb) {
    const int row = blockIdx.x, tid = threadIdx.x;
    const float4 xv = ((const float4*)(x + (size_t)row * 1024))[tid];
    float s = xv.x + xv.y + xv.z + xv.w;
    float sq = xv.x * xv.x + xv.y * xv.y + xv.z * xv.z + xv.w * xv.w;
#pragma unroll
    for (int m = 1; m < 64; m <<= 1) { s += __shfl_xor(s, m); sq += __shfl_xor(sq, m); }
    __shared__ float red[8];
    int w = tid >> 6;
    if ((tid & 63) == 0) { red[w] = s; red[4 + w] = sq; }
    __syncthreads();
    s = red[0] + red[1] + red[2] + red[3];
    sq = red[4] + red[5] + red[6] + red[7];
    float mean = s * (1.f / 1024.f);
    float var = sq * (1.f / 1024.f) - mean * mean;
    float rstd = rsqrtf(var + 1e-5f);
    float4 gv = ((const float4*)g)[tid];
    float4 bv = ((const float4*)bt)[tid];
    float4 y;
    y.x = (xv.x - mean) * rstd * gv.x + bv.x;
    y.y = (xv.y - mean) * rstd * gv.y + bv.y;
    y.z = (xv.z - mean) * rstd * gv.z + bv.z;
    y.w = (xv.w - mean) * rstd * gv.w + bv.w;
    ((float4*)(yf + (size_t)row * 1024))[tid] = y;
    ushort4 u;
    u.x = f2bf(y.x); u.y = f2bf(y.y); u.z = f2bf(y.z); u.w = f2bf(y.w);
    ((ushort4*)(yb + (size_t)row * 1024))[tid] = u;
}

// ---------------- GEMM 128x128, BK=64 swizzled: C = A(M,K) * Bt(N,K)^T ------
// outb = bf16(relu(acc+bias))   (used for FFN1)
__global__ __launch_bounds__(256) void gemm_bt(const u16* __restrict__ A,
                                               const u16* __restrict__ Bt,
                                               const float* __restrict__ bias,
                                               u16* __restrict__ outb,
                                               int M, int N, int K) {
    __shared__ __align__(16) u16 As[128 * 64];
    __shared__ __align__(16) u16 Bs[128 * 64];
    const int tid = threadIdx.x;
    const int w = tid >> 6, l = tid & 63, ln = l & 15, quad = l >> 4;
    const int m0 = blockIdx.y * 128, n0 = blockIdx.x * 128;
    const int wm = (w >> 1) * 64, wn = (w & 1) * 64;
    floatx4 acc[4][4] = {};

    for (int k0 = 0; k0 < K; k0 += 64) {
        __syncthreads();
#pragma unroll
        for (int r = 0; r < 4; r++) {
            int o = tid + r * 256;          // chunk id, 8 chunks/row (64 bf16)
            int row = o >> 3, c = (o & 7) ^ (row & 7);
            gl_lds16(&A[(size_t)(m0 + row) * K + k0 + c * 8], &As[(w * 64 + r * 256) * 8]);
            gl_lds16(&Bt[(size_t)(n0 + row) * K + k0 + c * 8], &Bs[(w * 64 + r * 256) * 8]);
        }
        __syncthreads();
#pragma unroll
        for (int kk = 0; kk < 2; kk++) {
            short8 av[4], bv[4];
#pragma unroll
            for (int mt = 0; mt < 4; mt++) {
                int rr = wm + mt * 16 + ln;
                av[mt] = *(const short8*)&As[rr * 64 + (((kk * 4 + quad) ^ (rr & 7)) * 8)];
            }
#pragma unroll
            for (int nt = 0; nt < 4; nt++) {
                int rr = wn + nt * 16 + ln;
                bv[nt] = *(const short8*)&Bs[rr * 64 + (((kk * 4 + quad) ^ (rr & 7)) * 8)];
            }
#pragma unroll
            for (int mt = 0; mt < 4; mt++)
#pragma unroll
                for (int nt = 0; nt < 4; nt++)
                    acc[mt][nt] = mfma16(av[mt], bv[nt], acc[mt][nt]);
        }
    }

#pragma unroll
    for (int nt = 0; nt < 4; nt++) {
        int n = n0 + wn + nt * 16 + ln;
        float bval = bias[n];
#pragma unroll
        for (int mt = 0; mt < 4; mt++) {
#pragma unroll
            for (int r = 0; r < 4; r++) {
                int m = m0 + wm + mt * 16 + quad * 4 + r;
                float v = acc[mt][nt][r] + bval;
                outb[(size_t)m * N + n] = f2bf(fmaxf(v, 0.f));
            }
        }
    }
}

// ---------------- fused QKV GEMM: N=3072 segmented epilogue, BK=64 ----------
__global__ __launch_bounds__(256) void gemm_qkv(const u16* __restrict__ A,
                                                const u16* __restrict__ Bt,
                                                const float* __restrict__ bq,
                                                const float* __restrict__ bk,
                                                const float* __restrict__ bv,
                                                u16* __restrict__ qb,
                                                u16* __restrict__ kb,
                                                u16* __restrict__ vtb) {
    constexpr int K = 1024;
    __shared__ __align__(16) u16 As[128 * 64];
    __shared__ __align__(16) u16 Bs[128 * 64];
    const int tid = threadIdx.x;
    const int w = tid >> 6, l = tid & 63, ln = l & 15, quad = l >> 4;
    const int m0 = blockIdx.y * 128, n0 = blockIdx.x * 128;
    const int wm = (w >> 1) * 64, wn = (w & 1) * 64;
    floatx4 acc[4][4] = {};

    for (int k0 = 0; k0 < K; k0 += 64) {
        __syncthreads();
#pragma unroll
        for (int r = 0; r < 4; r++) {
            int o = tid + r * 256;
            int row = o >> 3, c = (o & 7) ^ (row & 7);
            gl_lds16(&A[(size_t)(m0 + row) * K + k0 + c * 8], &As[(w * 64 + r * 256) * 8]);
            gl_lds16(&Bt[(size_t)(n0 + row) * K + k0 + c * 8], &Bs[(w * 64 + r * 256) * 8]);
        }
        __syncthreads();
#pragma unroll
        for (int kk = 0; kk < 2; kk++) {
            short8 av[4], bv4[4];
#pragma unroll
            for (int mt = 0; mt < 4; mt++) {
                int rr = wm + mt * 16 + ln;
                av[mt] = *(const short8*)&As[rr * 64 + (((kk * 4 + quad) ^ (rr & 7)) * 8)];
            }
#pragma unroll
            for (int nt = 0; nt < 4; nt++) {
                int rr = wn + nt * 16 + ln;
                bv4[nt] = *(const short8*)&Bs[rr * 64 + (((kk * 4 + quad) ^ (rr & 7)) * 8)];
            }
#pragma unroll
            for (int mt = 0; mt < 4; mt++)
#pragma unroll
                for (int nt = 0; nt < 4; nt++)
                    acc[mt][nt] = mfma16(av[mt], bv4[nt], acc[mt][nt]);
        }
    }

    const int seg = (n0 + wn) >> 10;  // wave-uniform: 0=q, 1=k, 2=v
#pragma unroll
    for (int nt = 0; nt < 4; nt++) {
        int nl = (n0 + wn + nt * 16 + ln) & 1023;
        float bval = seg == 0 ? bq[nl] : (seg == 1 ? bk[nl] : bv[nl]);
#pragma unroll
        for (int mt = 0; mt < 4; mt++) {
#pragma unroll
            for (int r = 0; r < 4; r++) {
                int m = m0 + wm + mt * 16 + quad * 4 + r;
                float v = acc[mt][nt][r] + bval;
                if (seg == 0) {
                    qb[(size_t)m * 1024 + nl] = f2bf(v * QSCALE);
                } else if (seg == 1) {
                    kb[(size_t)m * 1024 + nl] = f2bf(v);
                } else {
                    int b_ = m >> 11, s = m & 2047, hh = nl >> 6, d = nl & 63;
                    vtb[(((size_t)(b_ * 16 + hh)) * 64 + d) * 2048 + s] = f2bf(v);
                }
            }
        }
    }
}

// ---------------- GEMM 128x64 tile, BK=64 (N=1024 shapes, 512 blocks) -------
// out = acc + bias + resid (fp32)
__global__ __launch_bounds__(256) void gemm_bt64(const u16* __restrict__ A,
                                                 const u16* __restrict__ Bt,
                                                 const float* __restrict__ bias,
                                                 const float* __restrict__ resid,
                                                 float* __restrict__ outf,
                                                 int N, int K) {
    __shared__ __align__(16) u16 As[128 * 64];
    __shared__ __align__(16) u16 Bs[64 * 64];
    const int tid = threadIdx.x;
    const int w = tid >> 6, l = tid & 63, ln = l & 15, quad = l >> 4;
    const int m0 = blockIdx.y * 128, n0 = blockIdx.x * 64;
    const int wm = (w >> 1) * 64, wn = (w & 1) * 32;
    floatx4 acc[4][2] = {};

    for (int k0 = 0; k0 < K; k0 += 64) {
        __syncthreads();
#pragma unroll
        for (int r = 0; r < 4; r++) {
            int o = tid + r * 256;
            int row = o >> 3, c = (o & 7) ^ (row & 7);
            gl_lds16(&A[(size_t)(m0 + row) * K + k0 + c * 8], &As[(w * 64 + r * 256) * 8]);
        }
#pragma unroll
        for (int r = 0; r < 2; r++) {
            int o = tid + r * 256;
            int row = o >> 3, c = (o & 7) ^ (row & 7);
            gl_lds16(&Bt[(size_t)(n0 + row) * K + k0 + c * 8], &Bs[(w * 64 + r * 256) * 8]);
        }
        __syncthreads();
#pragma unroll
        for (int kk = 0; kk < 2; kk++) {
            short8 av[4], bv2[2];
#pragma unroll
            for (int mt = 0; mt < 4; mt++) {
                int rr = wm + mt * 16 + ln;
                av[mt] = *(const short8*)&As[rr * 64 + (((kk * 4 + quad) ^ (rr & 7)) * 8)];
            }
#pragma unroll
            for (int nt = 0; nt < 2; nt++) {
                int rr = wn + nt * 16 + ln;
                bv2[nt] = *(const short8*)&Bs[rr * 64 + (((kk * 4 + quad) ^ (rr & 7)) * 8)];
            }
#pragma unroll
            for (int mt = 0; mt < 4; mt++)
#pragma unroll
                for (int nt = 0; nt < 2; nt++)
                    acc[mt][nt] = mfma16(av[mt], bv2[nt], acc[mt][nt]);
        }
    }

#pragma unroll
    for (int nt = 0; nt < 2; nt++) {
        int n = n0 + wn + nt * 16 + ln;
        float bval = bias[n];
#pragma unroll
        for (int mt = 0; mt < 4; mt++) {
#pragma unroll
            for (int r = 0; r < 4; r++) {
                int m = m0 + wm + mt * 16 + quad * 4 + r;
                outf[(size_t)m * N + n] = acc[mt][nt][r] + bval + resid[(size_t)m * N + n];
            }
        }
    }
}

// ---------------- fused attention with relative-position skew ----------------
// exp2-domain, no online max (logits O(+-5)); l = P . ones via MFMA.
// Q-tile 128 rows, 8 waves x 16 rows; K-tile 64. Er B-fragments read DIRECTLY
// from global (256KB table, L2-hot) -- no LDS band buffer. LDS 34KB -> high occ.
__global__ __launch_bounds__(512, 4) void attn_kernel(const u16* __restrict__ qb,
                                                      const u16* __restrict__ kb,
                                                      const u16* __restrict__ vtb,
                                                      const u16* __restrict__ erb,
                                                      u16* __restrict__ ob) {
    constexpr int S = 2048, D = 1024;
    const int s0 = blockIdx.x * 128, h = blockIdx.y, b = blockIdx.z;
    const int tid = threadIdx.x, w = tid >> 6, l = tid & 63, ln = l & 15, quad = l >> 4;

    __shared__ __align__(16) u16 Ks[64 * 64];        // K tile  [t][d-chunk swz]   8KB
    __shared__ __align__(16) u16 Vts[64 * 64];       // V^T tile [d][t-chunk swz]  8KB
    __shared__ __align__(16) u16 Ps[8][16 * 72];     // per-wave P, stride 72     18KB

    const u16* kbase = kb + ((size_t)b * S) * D + h * 64;
    const u16* vtbase = vtb + ((size_t)(b * 16 + h)) * 64 * S;

    const u16* qrow = qb + ((size_t)b * S + s0 + w * 16 + ln) * D + h * 64;
    short8 aq[2];
    aq[0] = *(const short8*)&qrow[quad * 8];
    aq[1] = *(const short8*)&qrow[32 + quad * 8];

    const short8 ones8 = {16256, 16256, 16256, 16256, 16256, 16256, 16256, 16256};  // bf16 1.0

    // per-r gather constants: window col = nt*16 + (ln + 15 - quad*4 - r)
    int srcl[4], carry[4];
#pragma unroll
    for (int r = 0; r < 4; r++) {
        srcl[r] = (l & 48) | ((ln + 15 - quad * 4 - r) & 15);
        carry[r] = (ln - quad * 4 - r) > 0 ? 1 : 0;
    }

    floatx4 accO[4] = {};
    floatx4 accL = {};
    const int srow_base = s0 + w * 16 + quad * 4;

    for (int t0 = 0; t0 < S; t0 += 64) {
        const bool bias_tile = (t0 <= s0 + 64);
        __syncthreads();
        {   // stage K (64x64) and V^T (64x64), 512 chunks each, swizzled source
            int row = tid >> 3, sc = (tid & 7) ^ (row & 7);
            gl_lds16(&kbase[(size_t)(t0 + row) * D + sc * 8], &Ks[w * 512]);
            gl_lds16(&vtbase[(size_t)row * S + t0 + sc * 8], &Vts[w * 512]);
        }
        __syncthreads();

        // S = Q K^T  (per wave: 16 rows x 64 cols)
        floatx4 sacc[4] = {};
#pragma unroll
        for (int kk = 0; kk < 2; kk++)
#pragma unroll
            for (int nt = 0; nt < 4; nt++) {
                int tr = nt * 16 + ln;
                short8 bk = *(const short8*)&Ks[tr * 64 + (((kk * 4 + quad) ^ (tr & 7)) * 8)];
                sacc[nt] = mfma16(aq[kk], bk, sacc[nt]);
            }
        // G = Q ErBand^T over this wave's 80-col window; Er direct from global
        floatx4 gacc[5] = {};
        if (bias_tile) {
            int jw0 = t0 - s0 - w * 16 + 2032;   // >= 0 for all bias tiles
#pragma unroll
            for (int i = 0; i < 5; i++) {
                int j = jw0 + i * 16 + ln;
                j = j > S - 1 ? S - 1 : j;       // clamped rows are masked out
                const u16* ep = erb + (size_t)j * 64;
                short8 e0 = *(const short8*)&ep[quad * 8];
                short8 e1 = *(const short8*)&ep[32 + quad * 8];
                gacc[i] = mfma16(aq[0], e0, gacc[i]);
                gacc[i] = mfma16(aq[1], e1, gacc[i]);
            }
        }

        // p = exp2(score + bias); store P tile (bf16) for the PV MFMA
#pragma unroll
        for (int r = 0; r < 4; r++) {
            const int rloc = quad * 4 + r;
            const int srow = srow_base + r;
            float sh[5];
            if (bias_tile) {
#pragma unroll
                for (int i = 0; i < 5; i++) sh[i] = __shfl(gacc[i][r], srcl[r]);
            }
#pragma unroll
            for (int nt = 0; nt < 4; nt++) {
                float xv = sacc[nt][r];
                if (bias_tile) {
                    float g = carry[r] ? sh[nt + 1] : sh[nt];
                    bool mk = (t0 + nt * 16 + ln) <= srow;
                    xv += mk ? g : 0.f;
                }
                float p = __builtin_amdgcn_exp2f(xv);
                Ps[w][rloc * 72 + nt * 16 + ln] = f2bf(p);
            }
        }

        // O += P V ; l += P . ones   (all MFMA)
#pragma unroll
        for (int kk = 0; kk < 2; kk++) {
            short8 pf = *(const short8*)&Ps[w][ln * 72 + kk * 32 + quad * 8];
#pragma unroll
            for (int nt = 0; nt < 4; nt++) {
                int dr = nt * 16 + ln;
                short8 bv = *(const short8*)&Vts[dr * 64 + (((kk * 4 + quad) ^ (dr & 7)) * 8)];
                accO[nt] = mfma16(pf, bv, accO[nt]);
            }
            accL = mfma16(pf, ones8, accL);
        }
    }

#pragma unroll
    for (int r = 0; r < 4; r++) {
        float inv = 1.f / accL[r];
        int srow = srow_base + r;
#pragma unroll
        for (int nt = 0; nt < 4; nt++) {
            ob[((size_t)b * S + srow) * D + h * 64 + nt * 16 + ln] = f2bf(accO[nt][r] * inv);
        }
    }
}

// ---------------- launch ----------------
extern "C" void kernel_launch(void* const* d_in, const int* in_sizes, int n_in,
                              void* d_out, int out_size, void* d_ws, size_t ws_size,
                              hipStream_t stream) {
    const float* x   = (const float*)d_in[0];
    const float* Wq  = (const float*)d_in[1];
    const float* bq  = (const float*)d_in[2];
    const float* Wk  = (const float*)d_in[3];
    const float* bk  = (const float*)d_in[4];
    const float* Wv  = (const float*)d_in[5];
    const float* bv  = (const float*)d_in[6];
    const float* Wo  = (const float*)d_in[7];
    const float* bo  = (const float*)d_in[8];
    const float* Er  = (const float*)d_in[9];
    const float* W1  = (const float*)d_in[10];
    const float* b1  = (const float*)d_in[11];
    const float* W2  = (const float*)d_in[12];
    const float* b2  = (const float*)d_in[13];
    const float* g1  = (const float*)d_in[14];
    const float* be1 = (const float*)d_in[15];
    const float* g2  = (const float*)d_in[16];
    const float* be2 = (const float*)d_in[17];
    float* out = (float*)d_out;

    char* ws = (char*)d_ws;
    size_t off = 0;
    auto alloc_f = [&](size_t n) { float* p = (float*)(ws + off); off += n * 4; return p; };
    auto alloc_h = [&](size_t n) { u16* p = (u16*)(ws + off); off += n * 2; return p; };

    float* x1f = alloc_f((size_t)4096 * 1024);
    float* x2f = alloc_f((size_t)4096 * 1024);
    float* x3f = alloc_f((size_t)4096 * 1024);
    u16* x1b = alloc_h((size_t)4096 * 1024);
    u16* x3b = alloc_h((size_t)4096 * 1024);
    u16* qbf = alloc_h((size_t)4096 * 1024);   // } these four are contiguous:
    u16* kbf = alloc_h((size_t)4096 * 1024);   // } 32MB, reused as hbf for FFN
    u16* vtb = alloc_h((size_t)4096 * 1024);   // }
    u16* aob = alloc_h((size_t)4096 * 1024);   // }
    u16* WqT = alloc_h((size_t)1024 * 1024);   // } WqT/WkT/WvT contiguous = fused
    u16* WkT = alloc_h((size_t)1024 * 1024);   // } QKV weight (N=3072, K=1024)
    u16* WvT = alloc_h((size_t)1024 * 1024);   // }
    u16* WoT = alloc_h((size_t)1024 * 1024);
    u16* W1T = alloc_h((size_t)1024 * 4096);
    u16* W2T = alloc_h((size_t)1024 * 4096);
    u16* Erb = alloc_h((size_t)2048 * 64);
    u16* hbf = qbf;  // FFN hidden (4096x4096 bf16 = 32MB) aliases q/k/vT/attout
    (void)WkT; (void)WvT;

    dim3 tb(32, 8);
    transpose4_1024<<<dim3(32, 32, 4), tb, 0, stream>>>(Wq, Wk, Wv, Wo, WqT);
    transpose_f32_to_bf16<<<dim3(128, 32), tb, 0, stream>>>(W1, W1T, 1024, 4096);
    transpose_f32_to_bf16<<<dim3(32, 128), tb, 0, stream>>>(W2, W2T, 4096, 1024);
    convert_to_bf16<<<512, 256, 0, stream>>>(Er, Erb, 2048 * 64);

    ln_kernel<<<4096, 256, 0, stream>>>(x, g1, be1, x1f, x1b);

    // fused QKV: q=(x1 Wq+bq)*QSCALE (exp2 domain), k=x1 Wk+bk, v->(b,h,d,s)
    gemm_qkv<<<dim3(24, 32), 256, 0, stream>>>(x1b, WqT, bq, bk, bv, qbf, kbf, vtb);

    attn_kernel<<<dim3(16, 16, 2), 512, 0, stream>>>(qbf, kbf, vtb, Erb, aob);

    // x2 = x1 + attout Wo + bo
    gemm_bt64<<<dim3(16, 32), 256, 0, stream>>>(aob, WoT, bo, x1f, x2f, 1024, 1024);

    ln_kernel<<<4096, 256, 0, stream>>>(x2f, g2, be2, x3f, x3b);

    // h = relu(x3 W1 + b1) ; y = x3 + h W2 + b2
    gemm_bt<<<dim3(32, 32), 256, 0, stream>>>(x3b, W1T, b1, hbf, 4096, 4096, 1024);
    gemm_bt64<<<dim3(16, 32), 256, 0, stream>>>(hbf, W2T, b2, x3f, out, 1024, 4096);
}